// Round 8
// baseline (318.880 us; speedup 1.0000x reference)
//
#include <hip/hip_runtime.h>

// ---------------------------------------------------------------------------
// AttentiveStateMLP fused forward, MI355X (gfx950) — two-kernel split, v2.
// Round-7 baseline (first clean split, zero spills): A=95us B=85us.
// Round-8 changes (one per kernel, both on verified code paths):
//  - Kernel A: balanced attention (round-3 verified): thread serves row wv of
//    its own sample; (lane&3)==wv threads also serve row 4. Wave critical
//    path 2.0x -> 1.25x.
//  - Kernel B: ctx loads (40 strided dwords, depend on nothing in B) hoisted
//    to kernel entry into 10 uint4 regs; enc+tok-proj compute hides their
//    HBM latency. ~112 peak regs, still under the 128 wall.
// ---------------------------------------------------------------------------

#define B_TOTAL 131072
#define NBLK    (B_TOTAL / 64)

typedef _Float16 f16;
typedef __attribute__((ext_vector_type(2))) _Float16 f16x2;
typedef __attribute__((ext_vector_type(8))) _Float16 f16x8;
typedef __attribute__((ext_vector_type(8))) __fp16   mfma8;
typedef __attribute__((ext_vector_type(4))) float    f32x4;

// ---- ws layout (u32 words) ------------------------------------------------
#define W_EW    0
#define W_TOKW  4608
#define W_QKVW  10752
#define W_WOW   29184      // merged-K Wo frags: 8 blocks used (of 16)
#define W_WPW   33280
#define W_ENCB  37376
#define W_TOKB  37520
#define W_QKVB  37840
#define W_BPB   38800
#define W_TOTAL 38928
#define OFF_CTX 38928      // + 160 * B_TOTAL dwords: ctx[(h*40+t*8+d2)][sample]

__device__ __forceinline__ unsigned pk_rne(float a, float b) {
    f16x2 r; r.x = (_Float16)a; r.y = (_Float16)b;   // C cast = RNE
    return __builtin_bit_cast(unsigned, r);
}

// ---------------------------------------------------------------------------
// prep: identical to round-7 passing version.
// ---------------------------------------------------------------------------
extern "C" __global__ void k_prep(
    const float* __restrict__ Wph, const float* __restrict__ bph,
    const float* __restrict__ Wob, const float* __restrict__ bob,
    const float* __restrict__ Wmi, const float* __restrict__ bmi,
    const float* __restrict__ Wpr, const float* __restrict__ bpr,
    const float* __restrict__ Wse, const float* __restrict__ bse,
    const float* __restrict__ Pph, const float* __restrict__ pbph,
    const float* __restrict__ Pob, const float* __restrict__ pbob,
    const float* __restrict__ Pmi, const float* __restrict__ pbmi,
    const float* __restrict__ Ppr, const float* __restrict__ pbpr,
    const float* __restrict__ Pse, const float* __restrict__ pbse,
    const float* __restrict__ Wqkv, const float* __restrict__ bqkv,
    const float* __restrict__ Wo,  const float* __restrict__ bo,
    const float* __restrict__ Wp,  const float* __restrict__ bp,
    unsigned* __restrict__ ws)
{
    int idx = blockIdx.x * 256 + threadIdx.x;
    if (idx >= W_TOTAL) return;
    float* wsf = (float*)ws;

    if (idx < W_TOKW) {
        int w2 = idx, blk = w2 >> 8, r = w2 & 255, lane = r >> 2, pr = r & 3;
        int nt = blk >> 1, ks = blk & 1;
        int n = nt * 16 + (lane & 15);
        float v[2];
#pragma unroll
        for (int e = 0; e < 2; e++) {
            int k = ks * 32 + ((lane >> 4) << 3) + pr * 2 + e;
            float val = 0.f;
            if (n < 64)       { if (k < 29) val = Wph[n*29 + k]; }
            else if (n < 96)  { int kk = k - 29; if (kk >= 0 && kk < 15) val = Wob[(n-64)*15 + kk]; }
            else if (n < 112) { int kk = k - 44; if (kk >= 0 && kk < 8)  val = Wmi[(n-96)*8  + kk]; }
            else if (n < 128) { int kk = k - 52; if (kk >= 0 && kk < 3)  val = Wpr[(n-112)*3 + kk]; }
            else              { int kk = k - 55; if (kk >= 0 && kk < 3)  val = Wse[(n-128)*3 + kk]; }
            v[e] = val;
        }
        ws[idx] = pk_rne(v[0], v[1]);
    } else if (idx < W_QKVW) {
        int w2 = idx - W_TOKW, blk = w2 >> 8, r = w2 & 255, lane = r >> 2, pr = r & 3;
        int t, nt, ks;
        if (blk < 8) { t = 0; nt = blk >> 1; ks = blk & 1; }
        else         { t = 1 + ((blk - 8) >> 2); nt = (blk - 8) & 3; ks = 0; }
        const float* P = (t==0)?Pph:(t==1)?Pob:(t==2)?Pmi:(t==3)?Ppr:Pse;
        int d = (t==0)?64:(t==1)?32:16;
        int n = nt * 16 + (lane & 15);
        float v[2];
#pragma unroll
        for (int e = 0; e < 2; e++) {
            int k = ks * 32 + ((lane >> 4) << 3) + pr * 2 + e;
            v[e] = (k < d) ? P[n*d + k] : 0.f;
        }
        ws[idx] = pk_rne(v[0], v[1]);
    } else if (idx < W_WOW) {
        int w2 = idx - W_QKVW, blk = w2 >> 8, r = w2 & 255, lane = r >> 2, pr = r & 3;
        int t, b2;
        if (blk < 24) { t = 0; b2 = blk; }
        else          { t = 1 + (blk - 24) / 12; b2 = (blk - 24) % 12; }
        int h, nt, ks;
        if (t == 0) { h = b2 / 6; int rem = b2 % 6; nt = rem >> 1; ks = rem & 1; }
        else        { h = b2 / 3; nt = b2 % 3; ks = 0; }
        const float* P = (t==0)?Pph:(t==1)?Pob:(t==2)?Pmi:(t==3)?Ppr:Pse;
        int d = (t==0)?64:(t==1)?32:16;
        int c = nt * 64 + h * 16 + (lane & 15);
        float v[2] = {0.f, 0.f};
#pragma unroll
        for (int e = 0; e < 2; e++) {
            int k = ks * 32 + ((lane >> 4) << 3) + pr * 2 + e;
            if (k < d) {
                float s = 0.f;
                for (int u = 0; u < 64; u++) s += Wqkv[c*64 + u] * P[u*d + k];
                v[e] = s;
            }
        }
        ws[idx] = pk_rne(v[0], v[1]);
    } else if (idx < W_WPW) {
        // merged-K=64 Wo fragments: blocks [ks2(2)][nt(4)] = 8; rest zero.
        int w2 = idx - W_WOW, blk = w2 >> 8, r = w2 & 255, lane = r >> 2, pr = r & 3;
        if (blk < 8) {
            int ks2 = blk >> 2, nt = blk & 3;
            int n = nt * 16 + (lane & 15);
            float v[2];
#pragma unroll
            for (int e = 0; e < 2; e++) {
                int k = ks2 * 32 + ((lane >> 4) << 3) + pr * 2 + e;
                int h = k >> 4, d = k & 15;
                v[e] = Wo[n*64 + h*16 + d];
            }
            ws[idx] = pk_rne(v[0], v[1]);
        } else ws[idx] = 0;
    } else if (idx < W_ENCB) {
        int w2 = idx - W_WPW, blk = w2 >> 8, r = w2 & 255, lane = r >> 2, pr = r & 3;
        int nt = blk >> 1, ks = blk & 1;
        int n = nt * 16 + (lane & 15);
        float v[2];
#pragma unroll
        for (int e = 0; e < 2; e++) {
            int k = ks * 32 + ((lane >> 4) << 3) + pr * 2 + e;
            v[e] = Wp[n*64 + k];
        }
        ws[idx] = pk_rne(v[0], v[1]);
    } else if (idx < W_TOKB) {
        int n = idx - W_ENCB;
        wsf[idx] = (n<64)?bph[n]:(n<96)?bob[n-64]:(n<112)?bmi[n-96]:(n<128)?bpr[n-112]:bse[n-128];
    } else if (idx < W_QKVB) {
        int r = idx - W_TOKB, t = r >> 6, u = r & 63;
        const float* pb = (t==0)?pbph:(t==1)?pbob:(t==2)?pbmi:(t==3)?pbpr:pbse;
        wsf[idx] = pb[u] + bo[u];
    } else if (idx < W_BPB) {
        int r = idx - W_QKVB, t = r / 192, c = r % 192;
        const float* pb = (t==0)?pbph:(t==1)?pbob:(t==2)?pbmi:(t==3)?pbpr:pbse;
        float s = bqkv[c];
        for (int u = 0; u < 64; u++) s += Wqkv[c*64 + u] * pb[u];
        wsf[idx] = s;
    } else {
        wsf[idx] = bp[idx - W_BPB];
    }
}

// ---------------------------------------------------------------------------
// shared helpers
// ---------------------------------------------------------------------------
__device__ __forceinline__ f32x4 MFMA(f16x8 a, f16x8 b, f32x4 c) {
    return __builtin_amdgcn_mfma_f32_16x16x32_f16(
        __builtin_bit_cast(mfma8, a), __builtin_bit_cast(mfma8, b), c, 0, 0, 0);
}

__device__ __forceinline__ f16x8 ldB(const unsigned* __restrict__ W, int wordBase, int blk, int lane) {
    uint4 v = *((const uint4*)(W + wordBase) + (blk * 64 + lane));
    return __builtin_bit_cast(f16x8, v);
}

__device__ __forceinline__ f16x8 ldA(const f16* p, int stride, int row, int kbase, int lg) {
    return *(const f16x8*)(p + row * stride + kbase + lg * 8);
}

__device__ __forceinline__ void stC16(f16* base, int stride, int m0, int col0,
                                      f32x4 c, int l15, int lg) {
    int col = col0 + l15;
    int r0  = m0 + lg * 4;
#pragma unroll
    for (int r = 0; r < 4; r++) base[(r0 + r) * stride + col] = (f16)c[r];
}

// ---------------------------------------------------------------------------
// Kernel A: enc + per-head QKV + balanced attention -> ctx to global ws.
// ---------------------------------------------------------------------------
extern "C" __global__ void __launch_bounds__(256, 2) k_mainA(
    const float* __restrict__ x, const unsigned* __restrict__ W,
    unsigned* __restrict__ ctxg)
{
    __shared__ __align__(16) f16 f_lds[64 * 168];    // 21504 B
    __shared__ __align__(16) char dyn[30976];        // xb | qkv stripes [64][242]

    const int tid  = threadIdx.x;
    const int lane = tid & 63;
    const int wv   = tid >> 6;
    const int l15  = lane & 15;
    const int lg   = lane >> 4;

    const float* wsf   = (const float*)W;
    const float* encb  = wsf + W_ENCB;
    const float* qkvbp = wsf + W_QKVB;

    // ---- phase 0: zero f + xb, stage x -> xb (fp16, stride 72) ------------
    {
        unsigned* fu = (unsigned*)f_lds;
        for (int i = tid; i < 5376; i += 256) fu[i] = 0;
        unsigned* du = (unsigned*)dyn;
        for (int i = tid; i < 2304; i += 256) du[i] = 0;
    }
    __syncthreads();
    {
        f16* xb = (f16*)dyn;
        const float* xp = x + (size_t)blockIdx.x * (64 * 58);
        for (int i = tid; i < 3712; i += 256) {
            int s = i / 58, k = i - s * 58;
            xb[s * 72 + k] = (f16)xp[i];
        }
    }
    __syncthreads();

    // ---- phase 1: encoders via MFMA, relu -> f_lds ------------------------
    {
        f32x4 accE[3][4];
#pragma unroll
        for (int i = 0; i < 3; i++) {
            int nt = wv + i * 4;
            if (nt < 9) {
                float be = encb[nt * 16 + l15];
#pragma unroll
                for (int mt = 0; mt < 4; mt++) accE[i][mt] = (f32x4){be, be, be, be};
            }
        }
#pragma unroll
        for (int ks = 0; ks < 2; ks++) {
            f16x8 a[4];
#pragma unroll
            for (int mt = 0; mt < 4; mt++) {
                const char* p = dyn + (mt * 16 + l15) * 144 + ks * 64 + lg * 16;
                a[mt] = *(const f16x8*)p;
            }
#pragma unroll
            for (int i = 0; i < 3; i++) {
                int nt = wv + i * 4;
                if (nt < 9) {
                    f16x8 b = ldB(W, W_EW, nt * 2 + ks, lane);
#pragma unroll
                    for (int mt = 0; mt < 4; mt++) accE[i][mt] = MFMA(a[mt], b, accE[i][mt]);
                }
            }
        }
#pragma unroll
        for (int i = 0; i < 3; i++) {
            int nt = wv + i * 4;
            if (nt < 9) {
#pragma unroll
                for (int mt = 0; mt < 4; mt++) {
                    f32x4 c = accE[i][mt];
#pragma unroll
                    for (int r = 0; r < 4; r++) c[r] = fmaxf(c[r], 0.f);
                    stC16(f_lds, 168, mt * 16, nt * 16, c, l15, lg);
                }
            }
        }
    }
    __syncthreads();

    f16* qkv = (f16*)dyn;
    const int tokOff[5] = {0, 64, 96, 112, 128};

    // ---- do_qkv (round-1 verbatim; stripe cols: q t*48 | k t*48+16 | v +32)
    auto do_qkv = [&](int h) {
        const int qkvBase[5] = {0, 24, 36, 48, 60};
#pragma unroll
        for (int t = 0; t < 5; t++) {
            f32x4 aq[3];
#pragma unroll
            for (int nt = 0; nt < 3; nt++) {
                float bb = qkvbp[t * 192 + nt * 64 + h * 16 + l15];
                aq[nt] = (f32x4){bb, bb, bb, bb};
            }
#pragma unroll
            for (int ks = 0; ks < 2; ks++) {
                if (ks == 0 || t == 0) {
                    f16x8 a = ldA(f_lds, 168, wv * 16 + l15, tokOff[t] + ks * 32, lg);
#pragma unroll
                    for (int nt = 0; nt < 3; nt++) {
                        int blk = qkvBase[t] + ((t == 0) ? (h * 6 + nt * 2 + ks) : (h * 3 + nt));
                        f16x8 b = ldB(W, W_QKVW, blk, lane);
                        aq[nt] = MFMA(a, b, aq[nt]);
                    }
                }
            }
#pragma unroll
            for (int nt = 0; nt < 3; nt++)
                stC16(qkv, 242, wv * 16, t * 48 + nt * 16, aq[nt], l15, lg);
        }
    };

    // ---- do_att BALANCED (round-3 verified scheme on round-1 layout) ------
    // Thread serves row wv of its own sample (s = lane); threads with
    // (lane&3)==wv also serve row 4. Every wave: 1.25 row-tasks/thread.
    auto do_att = [&](int h) {
        const int s = lane;
        const int sglob = blockIdx.x * 64 + s;
        const f16x2* qr2 = (const f16x2*)(qkv + s * 242);
        const bool do4 = ((lane & 3) == wv);
        float q0[16], q4[16];
#pragma unroll
        for (int d2 = 0; d2 < 8; d2++) {
            f16x2 p = qr2[wv * 24 + d2];
            q0[2*d2] = (float)p.x; q0[2*d2+1] = (float)p.y;
        }
        if (do4) {
#pragma unroll
            for (int d2 = 0; d2 < 8; d2++) {
                f16x2 p = qr2[96 + d2];
                q4[2*d2] = (float)p.x; q4[2*d2+1] = (float)p.y;
            }
        }
        float p0[5], p4[5];
#pragma unroll
        for (int j = 0; j < 5; j++) {
            float a0 = 0.f, a4 = 0.f;
#pragma unroll
            for (int d2 = 0; d2 < 8; d2++) {
                f16x2 kp = qr2[j * 24 + 8 + d2];
                float k0 = (float)kp.x, k1 = (float)kp.y;
                a0 += q0[2*d2] * k0 + q0[2*d2+1] * k1;
                if (do4) a4 += q4[2*d2] * k0 + q4[2*d2+1] * k1;
            }
            p0[j] = a0 * 0.25f; p4[j] = do4 ? a4 * 0.25f : 0.f;
        }
        auto softmax5 = [](float* sc) {
            float m = fmaxf(fmaxf(fmaxf(sc[0], sc[1]), fmaxf(sc[2], sc[3])), sc[4]);
            float l = 0.f;
#pragma unroll
            for (int j = 0; j < 5; j++) { sc[j] = __expf(sc[j] - m); l += sc[j]; }
            float r = 1.f / l;
#pragma unroll
            for (int j = 0; j < 5; j++) sc[j] *= r;
        };
        softmax5(p0);
        softmax5(p4);
        float c0[16], c4[16];
#pragma unroll
        for (int d = 0; d < 16; d++) { c0[d] = 0.f; c4[d] = 0.f; }
#pragma unroll
        for (int j = 0; j < 5; j++) {
#pragma unroll
            for (int d2 = 0; d2 < 8; d2++) {
                f16x2 vp = qr2[j * 24 + 16 + d2];
                float v0 = (float)vp.x, v1 = (float)vp.y;
                c0[2*d2]   += p0[j] * v0;
                c0[2*d2+1] += p0[j] * v1;
                if (do4) { c4[2*d2] += p4[j] * v0; c4[2*d2+1] += p4[j] * v1; }
            }
        }
        auto wrctx = [&](int i, const float* c) {
            unsigned* cg = ctxg + OFF_CTX + (size_t)(h * 40 + i * 8) * B_TOTAL + sglob;
#pragma unroll
            for (int d2 = 0; d2 < 8; d2++)
                cg[(size_t)d2 * B_TOTAL] = pk_rne(c[2*d2], c[2*d2+1]);
        };
        wrctx(wv, c0);
        if (do4) wrctx(4, c4);
    };

    // ---- phase 2: head pipeline (2 barriers/head, no wo) ------------------
    do_qkv(0);
    __syncthreads();
    for (int h = 0; h < 4; h++) {
        do_att(h);
        __syncthreads();            // stripe reads done before next head's writes
        if (h < 3) { do_qkv(h + 1); __syncthreads(); }
    }
}

// ---------------------------------------------------------------------------
// Kernel B: ctx PREFETCHED at entry; enc recompute + tok-proj + merged Wo
//           (K=64) + LN + pool + Wp.
// ---------------------------------------------------------------------------
extern "C" __global__ void __launch_bounds__(256, 2) k_mainB(
    const float* __restrict__ x,
    const float* __restrict__ gamma, const float* __restrict__ beta,
    const unsigned* __restrict__ W, float* __restrict__ out)
{
    __shared__ __align__(16) f16 f_lds[64 * 168];    // 21504 B
    __shared__ __align__(16) char dyn[9216];         // xb | plA  [64][72] f16

    const int tid  = threadIdx.x;
    const int lane = tid & 63;
    const int wv   = tid >> 6;
    const int l15  = lane & 15;
    const int lg   = lane >> 4;

    const float* wsf   = (const float*)W;
    const float* encb  = wsf + W_ENCB;
    const float* tokbp = wsf + W_TOKB;
    const float* bpp   = wsf + W_BPB;

    // ---- phase -1: ISSUE ctx loads now (depend on nothing computed here).
    // 10 uint4 (40 VGPRs) stay live across enc/tok-proj; vmcnt waits land at
    // the Wo use site, so enc+tok-proj compute hides the HBM latency.
    uint4 ctxr[2][5];
    {
        const int sg = blockIdx.x * 64 + wv * 16 + l15;
#pragma unroll
        for (int ks2 = 0; ks2 < 2; ks2++) {
            const int hh = ks2 * 2 + (lg >> 1);
#pragma unroll
            for (int t = 0; t < 5; t++) {
                const unsigned* cp = W + OFF_CTX +
                    (size_t)(hh * 40 + t * 8 + (lg & 1) * 4) * B_TOTAL + sg;
                ctxr[ks2][t].x = cp[0];
                ctxr[ks2][t].y = cp[(size_t)B_TOTAL];
                ctxr[ks2][t].z = cp[(size_t)2 * B_TOTAL];
                ctxr[ks2][t].w = cp[(size_t)3 * B_TOTAL];
            }
        }
    }

    // ---- phase 0: zero f + xb, stage x ------------------------------------
    {
        unsigned* fu = (unsigned*)f_lds;
        for (int i = tid; i < 5376; i += 256) fu[i] = 0;
        unsigned* du = (unsigned*)dyn;
        for (int i = tid; i < 2304; i += 256) du[i] = 0;
    }
    __syncthreads();
    {
        f16* xb = (f16*)dyn;
        const float* xp = x + (size_t)blockIdx.x * (64 * 58);
        for (int i = tid; i < 3712; i += 256) {
            int s = i / 58, k = i - s * 58;
            xb[s * 72 + k] = (f16)xp[i];
        }
    }
    __syncthreads();

    // ---- phase 1: encoders (identical to A -> bit-identical f) ------------
    {
        f32x4 accE[3][4];
#pragma unroll
        for (int i = 0; i < 3; i++) {
            int nt = wv + i * 4;
            if (nt < 9) {
                float be = encb[nt * 16 + l15];
#pragma unroll
                for (int mt = 0; mt < 4; mt++) accE[i][mt] = (f32x4){be, be, be, be};
            }
        }
#pragma unroll
        for (int ks = 0; ks < 2; ks++) {
            f16x8 a[4];
#pragma unroll
            for (int mt = 0; mt < 4; mt++) {
                const char* p = dyn + (mt * 16 + l15) * 144 + ks * 64 + lg * 16;
                a[mt] = *(const f16x8*)p;
            }
#pragma unroll
            for (int i = 0; i < 3; i++) {
                int nt = wv + i * 4;
                if (nt < 9) {
                    f16x8 b = ldB(W, W_EW, nt * 2 + ks, lane);
#pragma unroll
                    for (int mt = 0; mt < 4; mt++) accE[i][mt] = MFMA(a[mt], b, accE[i][mt]);
                }
            }
        }
#pragma unroll
        for (int i = 0; i < 3; i++) {
            int nt = wv + i * 4;
            if (nt < 9) {
#pragma unroll
                for (int mt = 0; mt < 4; mt++) {
                    f32x4 c = accE[i][mt];
#pragma unroll
                    for (int r = 0; r < 4; r++) c[r] = fmaxf(c[r], 0.f);
                    stC16(f_lds, 168, mt * 16, nt * 16, c, l15, lg);
                }
            }
        }
    }
    __syncthreads();

    // ---- phase 2: h-frags = tok-proj + merged Wo --------------------------
    f32x4 hf[5][4];
    const int tokOff[5] = {0, 64, 96, 112, 128};

    {   // token projection (round-1 verbatim)
        const int tokBase[5] = {0, 8, 12, 16, 20};
#pragma unroll
        for (int t = 0; t < 5; t++)
#pragma unroll
            for (int nt = 0; nt < 4; nt++) {
                float bb = tokbp[t * 64 + nt * 16 + l15];
                hf[t][nt] = (f32x4){bb, bb, bb, bb};
            }
#pragma unroll
        for (int t = 0; t < 5; t++) {
#pragma unroll
            for (int ks = 0; ks < 2; ks++) {
                if (ks == 0 || t == 0) {
                    f16x8 a = ldA(f_lds, 168, wv * 16 + l15, tokOff[t] + ks * 32, lg);
#pragma unroll
                    for (int nt = 0; nt < 4; nt++) {
                        int blk = (t == 0) ? (nt * 2 + ks) : (tokBase[t] + nt);
                        f16x8 b = ldB(W, W_TOKW, blk, lane);
                        hf[t][nt] = MFMA(a, b, hf[t][nt]);
                    }
                }
            }
        }
    }

    {   // merged Wo: hf[t][nt] += ctx(t) @ Wo, K=64 over (head,dim)
#pragma unroll
        for (int ks2 = 0; ks2 < 2; ks2++) {
            f16x8 bfr[4];
#pragma unroll
            for (int nt = 0; nt < 4; nt++) bfr[nt] = ldB(W, W_WOW, ks2 * 4 + nt, lane);
#pragma unroll
            for (int t = 0; t < 5; t++) {
                f16x8 a = __builtin_bit_cast(f16x8, ctxr[ks2][t]);
#pragma unroll
                for (int nt = 0; nt < 4; nt++) hf[t][nt] = MFMA(a, bfr[nt], hf[t][nt]);
            }
        }
    }

    // ---- phase 3: LN per (sample, token), pool ----------------------------
    float g4[4], b4[4];
#pragma unroll
    for (int nt = 0; nt < 4; nt++) { g4[nt] = gamma[nt * 16 + l15]; b4[nt] = beta[nt * 16 + l15]; }
    f32x4 pool[4];
#pragma unroll
    for (int nt = 0; nt < 4; nt++) pool[nt] = (f32x4){0.f, 0.f, 0.f, 0.f};
#pragma unroll
    for (int t = 0; t < 5; t++) {
#pragma unroll
        for (int r = 0; r < 4; r++) {
            float sm = hf[t][0][r] + hf[t][1][r] + hf[t][2][r] + hf[t][3][r];
            sm += __shfl_xor(sm, 1); sm += __shfl_xor(sm, 2);
            sm += __shfl_xor(sm, 4); sm += __shfl_xor(sm, 8);
            float mu = sm * 0.015625f;
            float vs = 0.f;
#pragma unroll
            for (int nt = 0; nt < 4; nt++) { float d = hf[t][nt][r] - mu; vs += d * d; }
            vs += __shfl_xor(vs, 1); vs += __shfl_xor(vs, 2);
            vs += __shfl_xor(vs, 4); vs += __shfl_xor(vs, 8);
            float rs = rsqrtf(vs * 0.015625f + 1e-5f);
#pragma unroll
            for (int nt = 0; nt < 4; nt++)
                pool[nt][r] += (hf[t][nt][r] - mu) * rs * g4[nt] + b4[nt];
        }
    }
    __syncthreads();   // all xb/enc traffic long done; reuse dyn for plA
    {
        f16* plA = (f16*)dyn;
#pragma unroll
        for (int nt = 0; nt < 4; nt++) {
#pragma unroll
            for (int r = 0; r < 4; r++)
                plA[(wv * 16 + lg * 4 + r) * 72 + nt * 16 + l15] = (f16)(pool[nt][r] * 0.2f);
        }
    }
    __syncthreads();

    // ---- phase 4: out = relu(pooled @ Wp^T + bp), direct stores -----------
    {
        f32x4 accP[8];
#pragma unroll
        for (int n2 = 0; n2 < 8; n2++) {
            float bb = bpp[n2 * 16 + l15];
            accP[n2] = (f32x4){bb, bb, bb, bb};
        }
#pragma unroll
        for (int ks = 0; ks < 2; ks++) {
            const char* p = dyn + (wv * 16 + l15) * 144 + ks * 64 + lg * 16;
            f16x8 a = *(const f16x8*)p;
#pragma unroll
            for (int n2 = 0; n2 < 8; n2++) {
                f16x8 b = ldB(W, W_WPW, n2 * 2 + ks, lane);
                accP[n2] = MFMA(a, b, accP[n2]);
            }
        }
        float* og = out + (size_t)blockIdx.x * (64 * 128);
#pragma unroll
        for (int n2 = 0; n2 < 8; n2++) {
#pragma unroll
            for (int r = 0; r < 4; r++)
                og[(wv * 16 + lg * 4 + r) * 128 + n2 * 16 + l15] = fmaxf(accP[n2][r], 0.f);
        }
    }
}

// ---------------------------------------------------------------------------
extern "C" void kernel_launch(void* const* d_in, const int* in_sizes, int n_in,
                              void* d_out, int out_size, void* d_ws, size_t ws_size,
                              hipStream_t stream)
{
    const float* x      = (const float*)d_in[0];
    const float* W_phys = (const float*)d_in[1];
    const float* b_phys = (const float*)d_in[2];
    const float* W_obj  = (const float*)d_in[3];
    const float* b_obj  = (const float*)d_in[4];
    const float* W_mine = (const float*)d_in[5];
    const float* b_mine = (const float*)d_in[6];
    const float* W_prog = (const float*)d_in[7];
    const float* b_prog = (const float*)d_in[8];
    const float* W_seq  = (const float*)d_in[9];
    const float* b_seq  = (const float*)d_in[10];
    const float* P_phys = (const float*)d_in[11];
    const float* pb_phys= (const float*)d_in[12];
    const float* P_obj  = (const float*)d_in[13];
    const float* pb_obj = (const float*)d_in[14];
    const float* P_mine = (const float*)d_in[15];
    const float* pb_mine= (const float*)d_in[16];
    const float* P_prog = (const float*)d_in[17];
    const float* pb_prog= (const float*)d_in[18];
    const float* P_seq  = (const float*)d_in[19];
    const float* pb_seq = (const float*)d_in[20];
    const float* Wqkv   = (const float*)d_in[21];
    const float* bqkv   = (const float*)d_in[22];
    const float* Wo     = (const float*)d_in[23];
    const float* bo     = (const float*)d_in[24];
    const float* gamma  = (const float*)d_in[25];
    const float* beta   = (const float*)d_in[26];
    const float* Wp     = (const float*)d_in[27];
    const float* bp     = (const float*)d_in[28];

    unsigned* ws = (unsigned*)d_ws;

    k_prep<<<(W_TOTAL + 255) / 256, 256, 0, stream>>>(
        W_phys, b_phys, W_obj, b_obj, W_mine, b_mine, W_prog, b_prog, W_seq, b_seq,
        P_phys, pb_phys, P_obj, pb_obj, P_mine, pb_mine, P_prog, pb_prog, P_seq, pb_seq,
        Wqkv, bqkv, Wo, bo, Wp, bp, ws);

    k_mainA<<<NBLK, 256, 0, stream>>>(x, ws, ws);
    k_mainB<<<NBLK, 256, 0, stream>>>(x, gamma, beta, ws, (float*)d_out);
}

// Round 9
// 281.324 us; speedup vs baseline: 1.1335x; 1.1335x over previous
//
#include <hip/hip_runtime.h>

// ---------------------------------------------------------------------------
// AttentiveStateMLP fused forward, MI355X (gfx950) — two-kernel split, v3.
// Round-9: A reverted to round-7 exact form (95us, VGPR 84; round-8's
// "balanced" attention raised static VGPR to 124 and cost occupancy).
// B keeps the ctx prefetch but issues it AFTER phase-0's last barrier and
// BEFORE the encoder MFMAs, so the compiler's forced vmcnt(0) drain at the
// post-enc barrier lands after ~18 MFMAs of cover instead of immediately.
// ---------------------------------------------------------------------------

#define B_TOTAL 131072
#define NBLK    (B_TOTAL / 64)

typedef _Float16 f16;
typedef __attribute__((ext_vector_type(2))) _Float16 f16x2;
typedef __attribute__((ext_vector_type(8))) _Float16 f16x8;
typedef __attribute__((ext_vector_type(8))) __fp16   mfma8;
typedef __attribute__((ext_vector_type(4))) float    f32x4;

// ---- ws layout (u32 words) ------------------------------------------------
#define W_EW    0
#define W_TOKW  4608
#define W_QKVW  10752
#define W_WOW   29184      // merged-K Wo frags: 8 blocks used (of 16)
#define W_WPW   33280
#define W_ENCB  37376
#define W_TOKB  37520
#define W_QKVB  37840
#define W_BPB   38800
#define W_TOTAL 38928
#define OFF_CTX 38928      // + 160 * B_TOTAL dwords: ctx[(h*40+t*8+d2)][sample]

__device__ __forceinline__ unsigned pk_rne(float a, float b) {
    f16x2 r; r.x = (_Float16)a; r.y = (_Float16)b;   // C cast = RNE
    return __builtin_bit_cast(unsigned, r);
}

// ---------------------------------------------------------------------------
// prep: identical to round-7 passing version.
// ---------------------------------------------------------------------------
extern "C" __global__ void k_prep(
    const float* __restrict__ Wph, const float* __restrict__ bph,
    const float* __restrict__ Wob, const float* __restrict__ bob,
    const float* __restrict__ Wmi, const float* __restrict__ bmi,
    const float* __restrict__ Wpr, const float* __restrict__ bpr,
    const float* __restrict__ Wse, const float* __restrict__ bse,
    const float* __restrict__ Pph, const float* __restrict__ pbph,
    const float* __restrict__ Pob, const float* __restrict__ pbob,
    const float* __restrict__ Pmi, const float* __restrict__ pbmi,
    const float* __restrict__ Ppr, const float* __restrict__ pbpr,
    const float* __restrict__ Pse, const float* __restrict__ pbse,
    const float* __restrict__ Wqkv, const float* __restrict__ bqkv,
    const float* __restrict__ Wo,  const float* __restrict__ bo,
    const float* __restrict__ Wp,  const float* __restrict__ bp,
    unsigned* __restrict__ ws)
{
    int idx = blockIdx.x * 256 + threadIdx.x;
    if (idx >= W_TOTAL) return;
    float* wsf = (float*)ws;

    if (idx < W_TOKW) {
        int w2 = idx, blk = w2 >> 8, r = w2 & 255, lane = r >> 2, pr = r & 3;
        int nt = blk >> 1, ks = blk & 1;
        int n = nt * 16 + (lane & 15);
        float v[2];
#pragma unroll
        for (int e = 0; e < 2; e++) {
            int k = ks * 32 + ((lane >> 4) << 3) + pr * 2 + e;
            float val = 0.f;
            if (n < 64)       { if (k < 29) val = Wph[n*29 + k]; }
            else if (n < 96)  { int kk = k - 29; if (kk >= 0 && kk < 15) val = Wob[(n-64)*15 + kk]; }
            else if (n < 112) { int kk = k - 44; if (kk >= 0 && kk < 8)  val = Wmi[(n-96)*8  + kk]; }
            else if (n < 128) { int kk = k - 52; if (kk >= 0 && kk < 3)  val = Wpr[(n-112)*3 + kk]; }
            else              { int kk = k - 55; if (kk >= 0 && kk < 3)  val = Wse[(n-128)*3 + kk]; }
            v[e] = val;
        }
        ws[idx] = pk_rne(v[0], v[1]);
    } else if (idx < W_QKVW) {
        int w2 = idx - W_TOKW, blk = w2 >> 8, r = w2 & 255, lane = r >> 2, pr = r & 3;
        int t, nt, ks;
        if (blk < 8) { t = 0; nt = blk >> 1; ks = blk & 1; }
        else         { t = 1 + ((blk - 8) >> 2); nt = (blk - 8) & 3; ks = 0; }
        const float* P = (t==0)?Pph:(t==1)?Pob:(t==2)?Pmi:(t==3)?Ppr:Pse;
        int d = (t==0)?64:(t==1)?32:16;
        int n = nt * 16 + (lane & 15);
        float v[2];
#pragma unroll
        for (int e = 0; e < 2; e++) {
            int k = ks * 32 + ((lane >> 4) << 3) + pr * 2 + e;
            v[e] = (k < d) ? P[n*d + k] : 0.f;
        }
        ws[idx] = pk_rne(v[0], v[1]);
    } else if (idx < W_WOW) {
        int w2 = idx - W_QKVW, blk = w2 >> 8, r = w2 & 255, lane = r >> 2, pr = r & 3;
        int t, b2;
        if (blk < 24) { t = 0; b2 = blk; }
        else          { t = 1 + (blk - 24) / 12; b2 = (blk - 24) % 12; }
        int h, nt, ks;
        if (t == 0) { h = b2 / 6; int rem = b2 % 6; nt = rem >> 1; ks = rem & 1; }
        else        { h = b2 / 3; nt = b2 % 3; ks = 0; }
        const float* P = (t==0)?Pph:(t==1)?Pob:(t==2)?Pmi:(t==3)?Ppr:Pse;
        int d = (t==0)?64:(t==1)?32:16;
        int c = nt * 64 + h * 16 + (lane & 15);
        float v[2] = {0.f, 0.f};
#pragma unroll
        for (int e = 0; e < 2; e++) {
            int k = ks * 32 + ((lane >> 4) << 3) + pr * 2 + e;
            if (k < d) {
                float s = 0.f;
                for (int u = 0; u < 64; u++) s += Wqkv[c*64 + u] * P[u*d + k];
                v[e] = s;
            }
        }
        ws[idx] = pk_rne(v[0], v[1]);
    } else if (idx < W_WPW) {
        // merged-K=64 Wo fragments: blocks [ks2(2)][nt(4)] = 8; rest zero.
        int w2 = idx - W_WOW, blk = w2 >> 8, r = w2 & 255, lane = r >> 2, pr = r & 3;
        if (blk < 8) {
            int ks2 = blk >> 2, nt = blk & 3;
            int n = nt * 16 + (lane & 15);
            float v[2];
#pragma unroll
            for (int e = 0; e < 2; e++) {
                int k = ks2 * 32 + ((lane >> 4) << 3) + pr * 2 + e;
                int h = k >> 4, d = k & 15;
                v[e] = Wo[n*64 + h*16 + d];
            }
            ws[idx] = pk_rne(v[0], v[1]);
        } else ws[idx] = 0;
    } else if (idx < W_ENCB) {
        int w2 = idx - W_WPW, blk = w2 >> 8, r = w2 & 255, lane = r >> 2, pr = r & 3;
        int nt = blk >> 1, ks = blk & 1;
        int n = nt * 16 + (lane & 15);
        float v[2];
#pragma unroll
        for (int e = 0; e < 2; e++) {
            int k = ks * 32 + ((lane >> 4) << 3) + pr * 2 + e;
            v[e] = Wp[n*64 + k];
        }
        ws[idx] = pk_rne(v[0], v[1]);
    } else if (idx < W_TOKB) {
        int n = idx - W_ENCB;
        wsf[idx] = (n<64)?bph[n]:(n<96)?bob[n-64]:(n<112)?bmi[n-96]:(n<128)?bpr[n-112]:bse[n-128];
    } else if (idx < W_QKVB) {
        int r = idx - W_TOKB, t = r >> 6, u = r & 63;
        const float* pb = (t==0)?pbph:(t==1)?pbob:(t==2)?pbmi:(t==3)?pbpr:pbse;
        wsf[idx] = pb[u] + bo[u];
    } else if (idx < W_BPB) {
        int r = idx - W_QKVB, t = r / 192, c = r % 192;
        const float* pb = (t==0)?pbph:(t==1)?pbob:(t==2)?pbmi:(t==3)?pbpr:pbse;
        float s = bqkv[c];
        for (int u = 0; u < 64; u++) s += Wqkv[c*64 + u] * pb[u];
        wsf[idx] = s;
    } else {
        wsf[idx] = bp[idx - W_BPB];
    }
}

// ---------------------------------------------------------------------------
// shared helpers
// ---------------------------------------------------------------------------
__device__ __forceinline__ f32x4 MFMA(f16x8 a, f16x8 b, f32x4 c) {
    return __builtin_amdgcn_mfma_f32_16x16x32_f16(
        __builtin_bit_cast(mfma8, a), __builtin_bit_cast(mfma8, b), c, 0, 0, 0);
}

__device__ __forceinline__ f16x8 ldB(const unsigned* __restrict__ W, int wordBase, int blk, int lane) {
    uint4 v = *((const uint4*)(W + wordBase) + (blk * 64 + lane));
    return __builtin_bit_cast(f16x8, v);
}

__device__ __forceinline__ f16x8 ldA(const f16* p, int stride, int row, int kbase, int lg) {
    return *(const f16x8*)(p + row * stride + kbase + lg * 8);
}

__device__ __forceinline__ void stC16(f16* base, int stride, int m0, int col0,
                                      f32x4 c, int l15, int lg) {
    int col = col0 + l15;
    int r0  = m0 + lg * 4;
#pragma unroll
    for (int r = 0; r < 4; r++) base[(r0 + r) * stride + col] = (f16)c[r];
}

// ---------------------------------------------------------------------------
// Kernel A: enc + per-head QKV + attention -> ctx to global ws.
// (round-7 exact form: VGPR 84, 95us, zero spill)
// ---------------------------------------------------------------------------
extern "C" __global__ void __launch_bounds__(256, 2) k_mainA(
    const float* __restrict__ x, const unsigned* __restrict__ W,
    unsigned* __restrict__ ctxg)
{
    __shared__ __align__(16) f16 f_lds[64 * 168];    // 21504 B
    __shared__ __align__(16) char dyn[30976];        // xb | qkv stripes [64][242]

    const int tid  = threadIdx.x;
    const int lane = tid & 63;
    const int wv   = tid >> 6;
    const int l15  = lane & 15;
    const int lg   = lane >> 4;

    const float* wsf   = (const float*)W;
    const float* encb  = wsf + W_ENCB;
    const float* qkvbp = wsf + W_QKVB;

    // ---- phase 0: zero f + xb, stage x -> xb (fp16, stride 72) ------------
    {
        unsigned* fu = (unsigned*)f_lds;
        for (int i = tid; i < 5376; i += 256) fu[i] = 0;
        unsigned* du = (unsigned*)dyn;
        for (int i = tid; i < 2304; i += 256) du[i] = 0;
    }
    __syncthreads();
    {
        f16* xb = (f16*)dyn;
        const float* xp = x + (size_t)blockIdx.x * (64 * 58);
        for (int i = tid; i < 3712; i += 256) {
            int s = i / 58, k = i - s * 58;
            xb[s * 72 + k] = (f16)xp[i];
        }
    }
    __syncthreads();

    // ---- phase 1: encoders via MFMA, relu -> f_lds ------------------------
    {
        f32x4 accE[3][4];
#pragma unroll
        for (int i = 0; i < 3; i++) {
            int nt = wv + i * 4;
            if (nt < 9) {
                float be = encb[nt * 16 + l15];
#pragma unroll
                for (int mt = 0; mt < 4; mt++) accE[i][mt] = (f32x4){be, be, be, be};
            }
        }
#pragma unroll
        for (int ks = 0; ks < 2; ks++) {
            f16x8 a[4];
#pragma unroll
            for (int mt = 0; mt < 4; mt++) {
                const char* p = dyn + (mt * 16 + l15) * 144 + ks * 64 + lg * 16;
                a[mt] = *(const f16x8*)p;
            }
#pragma unroll
            for (int i = 0; i < 3; i++) {
                int nt = wv + i * 4;
                if (nt < 9) {
                    f16x8 b = ldB(W, W_EW, nt * 2 + ks, lane);
#pragma unroll
                    for (int mt = 0; mt < 4; mt++) accE[i][mt] = MFMA(a[mt], b, accE[i][mt]);
                }
            }
        }
#pragma unroll
        for (int i = 0; i < 3; i++) {
            int nt = wv + i * 4;
            if (nt < 9) {
#pragma unroll
                for (int mt = 0; mt < 4; mt++) {
                    f32x4 c = accE[i][mt];
#pragma unroll
                    for (int r = 0; r < 4; r++) c[r] = fmaxf(c[r], 0.f);
                    stC16(f_lds, 168, mt * 16, nt * 16, c, l15, lg);
                }
            }
        }
    }
    __syncthreads();

    f16* qkv = (f16*)dyn;
    const int tokOff[5] = {0, 64, 96, 112, 128};

    // ---- do_qkv (round-1 verbatim; stripe cols: q t*48 | k t*48+16 | v +32)
    auto do_qkv = [&](int h) {
        const int qkvBase[5] = {0, 24, 36, 48, 60};
#pragma unroll
        for (int t = 0; t < 5; t++) {
            f32x4 aq[3];
#pragma unroll
            for (int nt = 0; nt < 3; nt++) {
                float bb = qkvbp[t * 192 + nt * 64 + h * 16 + l15];
                aq[nt] = (f32x4){bb, bb, bb, bb};
            }
#pragma unroll
            for (int ks = 0; ks < 2; ks++) {
                if (ks == 0 || t == 0) {
                    f16x8 a = ldA(f_lds, 168, wv * 16 + l15, tokOff[t] + ks * 32, lg);
#pragma unroll
                    for (int nt = 0; nt < 3; nt++) {
                        int blk = qkvBase[t] + ((t == 0) ? (h * 6 + nt * 2 + ks) : (h * 3 + nt));
                        f16x8 b = ldB(W, W_QKVW, blk, lane);
                        aq[nt] = MFMA(a, b, aq[nt]);
                    }
                }
            }
#pragma unroll
            for (int nt = 0; nt < 3; nt++)
                stC16(qkv, 242, wv * 16, t * 48 + nt * 16, aq[nt], l15, lg);
        }
    };

    // ---- do_att (round-7 exact: wave0 serves rows 0 and 4) -----------------
    auto do_att = [&](int h) {
        const int s    = tid & 63;
        const int role = wv;
        const int sglob = blockIdx.x * 64 + s;
        const f16x2* qr2 = (const f16x2*)(qkv + s * 242);
        float q0[16], q4[16];
#pragma unroll
        for (int d2 = 0; d2 < 8; d2++) {
            f16x2 p = qr2[role * 24 + d2];
            q0[2*d2] = (float)p.x; q0[2*d2+1] = (float)p.y;
        }
        if (role == 0) {
#pragma unroll
            for (int d2 = 0; d2 < 8; d2++) {
                f16x2 p = qr2[96 + d2];
                q4[2*d2] = (float)p.x; q4[2*d2+1] = (float)p.y;
            }
        }
        float p0[5], p4[5];
#pragma unroll
        for (int j = 0; j < 5; j++) {
            float a0 = 0.f, a4 = 0.f;
#pragma unroll
            for (int d2 = 0; d2 < 8; d2++) {
                f16x2 kp = qr2[j * 24 + 8 + d2];
                float k0 = (float)kp.x, k1 = (float)kp.y;
                a0 += q0[2*d2] * k0 + q0[2*d2+1] * k1;
                if (role == 0) a4 += q4[2*d2] * k0 + q4[2*d2+1] * k1;
            }
            p0[j] = a0 * 0.25f; p4[j] = a4 * 0.25f;
        }
        auto softmax5 = [](float* sc) {
            float m = fmaxf(fmaxf(fmaxf(sc[0], sc[1]), fmaxf(sc[2], sc[3])), sc[4]);
            float l = 0.f;
#pragma unroll
            for (int j = 0; j < 5; j++) { sc[j] = __expf(sc[j] - m); l += sc[j]; }
            float r = 1.f / l;
#pragma unroll
            for (int j = 0; j < 5; j++) sc[j] *= r;
        };
        softmax5(p0);
        if (role == 0) softmax5(p4);
        float c0[16], c4[16];
#pragma unroll
        for (int d = 0; d < 16; d++) { c0[d] = 0.f; c4[d] = 0.f; }
#pragma unroll
        for (int j = 0; j < 5; j++) {
#pragma unroll
            for (int d2 = 0; d2 < 8; d2++) {
                f16x2 vp = qr2[j * 24 + 16 + d2];
                float v0 = (float)vp.x, v1 = (float)vp.y;
                c0[2*d2]   += p0[j] * v0;
                c0[2*d2+1] += p0[j] * v1;
                if (role == 0) { c4[2*d2] += p4[j] * v0; c4[2*d2+1] += p4[j] * v1; }
            }
        }
        auto wrctx = [&](int i, const float* c) {
            unsigned* cg = ctxg + OFF_CTX + (size_t)(h * 40 + i * 8) * B_TOTAL + sglob;
#pragma unroll
            for (int d2 = 0; d2 < 8; d2++)
                cg[(size_t)d2 * B_TOTAL] = pk_rne(c[2*d2], c[2*d2+1]);
        };
        wrctx(role, c0);
        if (role == 0) wrctx(4, c4);
    };

    // ---- phase 2: head pipeline (2 barriers/head, no wo) ------------------
    do_qkv(0);
    __syncthreads();
    for (int h = 0; h < 4; h++) {
        do_att(h);
        __syncthreads();            // stripe reads done before next head's writes
        if (h < 3) { do_qkv(h + 1); __syncthreads(); }
    }
}

// ---------------------------------------------------------------------------
// Kernel B: ctx prefetched AFTER phase-0 (enc compute hides the latency);
//           enc recompute + tok-proj + merged Wo (K=64) + LN + pool + Wp.
// ---------------------------------------------------------------------------
extern "C" __global__ void __launch_bounds__(256, 2) k_mainB(
    const float* __restrict__ x,
    const float* __restrict__ gamma, const float* __restrict__ beta,
    const unsigned* __restrict__ W, float* __restrict__ out)
{
    __shared__ __align__(16) f16 f_lds[64 * 168];    // 21504 B
    __shared__ __align__(16) char dyn[9216];         // xb | plA  [64][72] f16

    const int tid  = threadIdx.x;
    const int lane = tid & 63;
    const int wv   = tid >> 6;
    const int l15  = lane & 15;
    const int lg   = lane >> 4;

    const float* wsf   = (const float*)W;
    const float* encb  = wsf + W_ENCB;
    const float* tokbp = wsf + W_TOKB;
    const float* bpp   = wsf + W_BPB;

    // ---- phase 0: zero f + xb, stage x ------------------------------------
    {
        unsigned* fu = (unsigned*)f_lds;
        for (int i = tid; i < 5376; i += 256) fu[i] = 0;
        unsigned* du = (unsigned*)dyn;
        for (int i = tid; i < 2304; i += 256) du[i] = 0;
    }
    __syncthreads();
    {
        f16* xb = (f16*)dyn;
        const float* xp = x + (size_t)blockIdx.x * (64 * 58);
        for (int i = tid; i < 3712; i += 256) {
            int s = i / 58, k = i - s * 58;
            xb[s * 72 + k] = (f16)xp[i];
        }
    }
    __syncthreads();

    // ---- ISSUE ctx loads here: no barrier until after the encoder MFMAs,
    // so the forced vmcnt drain at the post-enc barrier has ~18 MFMAs +
    // LDS traffic of cover. 10 uint4 = 40 VGPRs live through phase 1.
    uint4 ctxr[2][5];
    {
        const int sg = blockIdx.x * 64 + wv * 16 + l15;
#pragma unroll
        for (int ks2 = 0; ks2 < 2; ks2++) {
            const int hh = ks2 * 2 + (lg >> 1);
#pragma unroll
            for (int t = 0; t < 5; t++) {
                const unsigned* cp = W + OFF_CTX +
                    (size_t)(hh * 40 + t * 8 + (lg & 1) * 4) * B_TOTAL + sg;
                ctxr[ks2][t].x = cp[0];
                ctxr[ks2][t].y = cp[(size_t)B_TOTAL];
                ctxr[ks2][t].z = cp[(size_t)2 * B_TOTAL];
                ctxr[ks2][t].w = cp[(size_t)3 * B_TOTAL];
            }
        }
    }

    // ---- phase 1: encoders (identical to A -> bit-identical f) ------------
    {
        f32x4 accE[3][4];
#pragma unroll
        for (int i = 0; i < 3; i++) {
            int nt = wv + i * 4;
            if (nt < 9) {
                float be = encb[nt * 16 + l15];
#pragma unroll
                for (int mt = 0; mt < 4; mt++) accE[i][mt] = (f32x4){be, be, be, be};
            }
        }
#pragma unroll
        for (int ks = 0; ks < 2; ks++) {
            f16x8 a[4];
#pragma unroll
            for (int mt = 0; mt < 4; mt++) {
                const char* p = dyn + (mt * 16 + l15) * 144 + ks * 64 + lg * 16;
                a[mt] = *(const f16x8*)p;
            }
#pragma unroll
            for (int i = 0; i < 3; i++) {
                int nt = wv + i * 4;
                if (nt < 9) {
                    f16x8 b = ldB(W, W_EW, nt * 2 + ks, lane);
#pragma unroll
                    for (int mt = 0; mt < 4; mt++) accE[i][mt] = MFMA(a[mt], b, accE[i][mt]);
                }
            }
        }
#pragma unroll
        for (int i = 0; i < 3; i++) {
            int nt = wv + i * 4;
            if (nt < 9) {
#pragma unroll
                for (int mt = 0; mt < 4; mt++) {
                    f32x4 c = accE[i][mt];
#pragma unroll
                    for (int r = 0; r < 4; r++) c[r] = fmaxf(c[r], 0.f);
                    stC16(f_lds, 168, mt * 16, nt * 16, c, l15, lg);
                }
            }
        }
    }
    __syncthreads();

    // ---- phase 2: h-frags = tok-proj + merged Wo --------------------------
    f32x4 hf[5][4];
    const int tokOff[5] = {0, 64, 96, 112, 128};

    {   // token projection (round-1 verbatim)
        const int tokBase[5] = {0, 8, 12, 16, 20};
#pragma unroll
        for (int t = 0; t < 5; t++)
#pragma unroll
            for (int nt = 0; nt < 4; nt++) {
                float bb = tokbp[t * 64 + nt * 16 + l15];
                hf[t][nt] = (f32x4){bb, bb, bb, bb};
            }
#pragma unroll
        for (int t = 0; t < 5; t++) {
#pragma unroll
            for (int ks = 0; ks < 2; ks++) {
                if (ks == 0 || t == 0) {
                    f16x8 a = ldA(f_lds, 168, wv * 16 + l15, tokOff[t] + ks * 32, lg);
#pragma unroll
                    for (int nt = 0; nt < 4; nt++) {
                        int blk = (t == 0) ? (nt * 2 + ks) : (tokBase[t] + nt);
                        f16x8 b = ldB(W, W_TOKW, blk, lane);
                        hf[t][nt] = MFMA(a, b, hf[t][nt]);
                    }
                }
            }
        }
    }

    {   // merged Wo: hf[t][nt] += ctx(t) @ Wo, K=64 over (head,dim)
#pragma unroll
        for (int ks2 = 0; ks2 < 2; ks2++) {
            f16x8 bfr[4];
#pragma unroll
            for (int nt = 0; nt < 4; nt++) bfr[nt] = ldB(W, W_WOW, ks2 * 4 + nt, lane);
#pragma unroll
            for (int t = 0; t < 5; t++) {
                f16x8 a = __builtin_bit_cast(f16x8, ctxr[ks2][t]);
#pragma unroll
                for (int nt = 0; nt < 4; nt++) hf[t][nt] = MFMA(a, bfr[nt], hf[t][nt]);
            }
        }
    }

    // ---- phase 3: LN per (sample, token), pool ----------------------------
    float g4[4], b4[4];
#pragma unroll
    for (int nt = 0; nt < 4; nt++) { g4[nt] = gamma[nt * 16 + l15]; b4[nt] = beta[nt * 16 + l15]; }
    f32x4 pool[4];
#pragma unroll
    for (int nt = 0; nt < 4; nt++) pool[nt] = (f32x4){0.f, 0.f, 0.f, 0.f};
#pragma unroll
    for (int t = 0; t < 5; t++) {
#pragma unroll
        for (int r = 0; r < 4; r++) {
            float sm = hf[t][0][r] + hf[t][1][r] + hf[t][2][r] + hf[t][3][r];
            sm += __shfl_xor(sm, 1); sm += __shfl_xor(sm, 2);
            sm += __shfl_xor(sm, 4); sm += __shfl_xor(sm, 8);
            float mu = sm * 0.015625f;
            float vs = 0.f;
#pragma unroll
            for (int nt = 0; nt < 4; nt++) { float d = hf[t][nt][r] - mu; vs += d * d; }
            vs += __shfl_xor(vs, 1); vs += __shfl_xor(vs, 2);
            vs += __shfl_xor(vs, 4); vs += __shfl_xor(vs, 8);
            float rs = rsqrtf(vs * 0.015625f + 1e-5f);
#pragma unroll
            for (int nt = 0; nt < 4; nt++)
                pool[nt][r] += (hf[t][nt][r] - mu) * rs * g4[nt] + b4[nt];
        }
    }
    __syncthreads();   // all xb/enc traffic long done; reuse dyn for plA
    {
        f16* plA = (f16*)dyn;
#pragma unroll
        for (int nt = 0; nt < 4; nt++) {
#pragma unroll
            for (int r = 0; r < 4; r++)
                plA[(wv * 16 + lg * 4 + r) * 72 + nt * 16 + l15] = (f16)(pool[nt][r] * 0.2f);
        }
    }
    __syncthreads();

    // ---- phase 4: out = relu(pooled @ Wp^T + bp), direct stores -----------
    {
        f32x4 accP[8];
#pragma unroll
        for (int n2 = 0; n2 < 8; n2++) {
            float bb = bpp[n2 * 16 + l15];
            accP[n2] = (f32x4){bb, bb, bb, bb};
        }
#pragma unroll
        for (int ks = 0; ks < 2; ks++) {
            const char* p = dyn + (wv * 16 + l15) * 144 + ks * 64 + lg * 16;
            f16x8 a = *(const f16x8*)p;
#pragma unroll
            for (int n2 = 0; n2 < 8; n2++) {
                f16x8 b = ldB(W, W_WPW, n2 * 2 + ks, lane);
                accP[n2] = MFMA(a, b, accP[n2]);
            }
        }
        float* og = out + (size_t)blockIdx.x * (64 * 128);
#pragma unroll
        for (int n2 = 0; n2 < 8; n2++) {
#pragma unroll
            for (int r = 0; r < 4; r++)
                og[(wv * 16 + lg * 4 + r) * 128 + n2 * 16 + l15] = fmaxf(accP[n2][r], 0.f);
        }
    }
}

// ---------------------------------------------------------------------------
extern "C" void kernel_launch(void* const* d_in, const int* in_sizes, int n_in,
                              void* d_out, int out_size, void* d_ws, size_t ws_size,
                              hipStream_t stream)
{
    const float* x      = (const float*)d_in[0];
    const float* W_phys = (const float*)d_in[1];
    const float* b_phys = (const float*)d_in[2];
    const float* W_obj  = (const float*)d_in[3];
    const float* b_obj  = (const float*)d_in[4];
    const float* W_mine = (const float*)d_in[5];
    const float* b_mine = (const float*)d_in[6];
    const float* W_prog = (const float*)d_in[7];
    const float* b_prog = (const float*)d_in[8];
    const float* W_seq  = (const float*)d_in[9];
    const float* b_seq  = (const float*)d_in[10];
    const float* P_phys = (const float*)d_in[11];
    const float* pb_phys= (const float*)d_in[12];
    const float* P_obj  = (const float*)d_in[13];
    const float* pb_obj = (const float*)d_in[14];
    const float* P_mine = (const float*)d_in[15];
    const float* pb_mine= (const float*)d_in[16];
    const float* P_prog = (const float*)d_in[17];
    const float* pb_prog= (const float*)d_in[18];
    const float* P_seq  = (const float*)d_in[19];
    const float* pb_seq = (const float*)d_in[20];
    const float* Wqkv   = (const float*)d_in[21];
    const float* bqkv   = (const float*)d_in[22];
    const float* Wo     = (const float*)d_in[23];
    const float* bo     = (const float*)d_in[24];
    const float* gamma  = (const float*)d_in[25];
    const float* beta   = (const float*)d_in[26];
    const float* Wp     = (const float*)d_in[27];
    const float* bp     = (const float*)d_in[28];

    unsigned* ws = (unsigned*)d_ws;

    k_prep<<<(W_TOTAL + 255) / 256, 256, 0, stream>>>(
        W_phys, b_phys, W_obj, b_obj, W_mine, b_mine, W_prog, b_prog, W_seq, b_seq,
        P_phys, pb_phys, P_obj, pb_obj, P_mine, pb_mine, P_prog, pb_prog, P_seq, pb_seq,
        Wqkv, bqkv, Wo, bo, Wp, bp, ws);

    k_mainA<<<NBLK, 256, 0, stream>>>(x, ws, ws);
    k_mainB<<<NBLK, 256, 0, stream>>>(x, gamma, beta, ws, (float*)d_out);
}

// Round 10
// 273.068 us; speedup vs baseline: 1.1678x; 1.0302x over previous
//
#include <hip/hip_runtime.h>

// ---------------------------------------------------------------------------
// AttentiveStateMLP fused forward, MI355X (gfx950) — two-kernel split, v4.
// Round-10: single change vs round-9 (best, 281us): kernel A's attention
// scores use packed v_dot2_f32_f16 (fdot2) on f16x2 pairs instead of
// unpack-to-f32 + scalar fma. Score-phase VALU: 176 -> 40 ops per
// row-task/head; q stays packed (saves 8 VGPRs). dot8/fdot2 numerics are
// field-verified (round-3 passed with fdot2 scores). B byte-identical to
// round 9 (ctx prefetch after phase-0, enc compute hides HBM latency).
// ---------------------------------------------------------------------------

#define B_TOTAL 131072
#define NBLK    (B_TOTAL / 64)

typedef _Float16 f16;
typedef __attribute__((ext_vector_type(2))) _Float16 f16x2;
typedef __attribute__((ext_vector_type(8))) _Float16 f16x8;
typedef __attribute__((ext_vector_type(8))) __fp16   mfma8;
typedef __attribute__((ext_vector_type(4))) float    f32x4;

// ---- ws layout (u32 words) ------------------------------------------------
#define W_EW    0
#define W_TOKW  4608
#define W_QKVW  10752
#define W_WOW   29184      // merged-K Wo frags: 8 blocks used (of 16)
#define W_WPW   33280
#define W_ENCB  37376
#define W_TOKB  37520
#define W_QKVB  37840
#define W_BPB   38800
#define W_TOTAL 38928
#define OFF_CTX 38928      // + 160 * B_TOTAL dwords: ctx[(h*40+t*8+d2)][sample]

__device__ __forceinline__ unsigned pk_rne(float a, float b) {
    f16x2 r; r.x = (_Float16)a; r.y = (_Float16)b;   // C cast = RNE
    return __builtin_bit_cast(unsigned, r);
}

__device__ __forceinline__ float fdot2(f16x2 a, f16x2 b, float c) {
#if __has_builtin(__builtin_amdgcn_fdot2)
    typedef __fp16 hv2 __attribute__((ext_vector_type(2)));
    return __builtin_amdgcn_fdot2(__builtin_bit_cast(hv2, a), __builtin_bit_cast(hv2, b), c, false);
#else
    return c + (float)a.x * (float)b.x + (float)a.y * (float)b.y;
#endif
}

// ---------------------------------------------------------------------------
// prep: identical to round-7/9 passing version.
// ---------------------------------------------------------------------------
extern "C" __global__ void k_prep(
    const float* __restrict__ Wph, const float* __restrict__ bph,
    const float* __restrict__ Wob, const float* __restrict__ bob,
    const float* __restrict__ Wmi, const float* __restrict__ bmi,
    const float* __restrict__ Wpr, const float* __restrict__ bpr,
    const float* __restrict__ Wse, const float* __restrict__ bse,
    const float* __restrict__ Pph, const float* __restrict__ pbph,
    const float* __restrict__ Pob, const float* __restrict__ pbob,
    const float* __restrict__ Pmi, const float* __restrict__ pbmi,
    const float* __restrict__ Ppr, const float* __restrict__ pbpr,
    const float* __restrict__ Pse, const float* __restrict__ pbse,
    const float* __restrict__ Wqkv, const float* __restrict__ bqkv,
    const float* __restrict__ Wo,  const float* __restrict__ bo,
    const float* __restrict__ Wp,  const float* __restrict__ bp,
    unsigned* __restrict__ ws)
{
    int idx = blockIdx.x * 256 + threadIdx.x;
    if (idx >= W_TOTAL) return;
    float* wsf = (float*)ws;

    if (idx < W_TOKW) {
        int w2 = idx, blk = w2 >> 8, r = w2 & 255, lane = r >> 2, pr = r & 3;
        int nt = blk >> 1, ks = blk & 1;
        int n = nt * 16 + (lane & 15);
        float v[2];
#pragma unroll
        for (int e = 0; e < 2; e++) {
            int k = ks * 32 + ((lane >> 4) << 3) + pr * 2 + e;
            float val = 0.f;
            if (n < 64)       { if (k < 29) val = Wph[n*29 + k]; }
            else if (n < 96)  { int kk = k - 29; if (kk >= 0 && kk < 15) val = Wob[(n-64)*15 + kk]; }
            else if (n < 112) { int kk = k - 44; if (kk >= 0 && kk < 8)  val = Wmi[(n-96)*8  + kk]; }
            else if (n < 128) { int kk = k - 52; if (kk >= 0 && kk < 3)  val = Wpr[(n-112)*3 + kk]; }
            else              { int kk = k - 55; if (kk >= 0 && kk < 3)  val = Wse[(n-128)*3 + kk]; }
            v[e] = val;
        }
        ws[idx] = pk_rne(v[0], v[1]);
    } else if (idx < W_QKVW) {
        int w2 = idx - W_TOKW, blk = w2 >> 8, r = w2 & 255, lane = r >> 2, pr = r & 3;
        int t, nt, ks;
        if (blk < 8) { t = 0; nt = blk >> 1; ks = blk & 1; }
        else         { t = 1 + ((blk - 8) >> 2); nt = (blk - 8) & 3; ks = 0; }
        const float* P = (t==0)?Pph:(t==1)?Pob:(t==2)?Pmi:(t==3)?Ppr:Pse;
        int d = (t==0)?64:(t==1)?32:16;
        int n = nt * 16 + (lane & 15);
        float v[2];
#pragma unroll
        for (int e = 0; e < 2; e++) {
            int k = ks * 32 + ((lane >> 4) << 3) + pr * 2 + e;
            v[e] = (k < d) ? P[n*d + k] : 0.f;
        }
        ws[idx] = pk_rne(v[0], v[1]);
    } else if (idx < W_WOW) {
        int w2 = idx - W_QKVW, blk = w2 >> 8, r = w2 & 255, lane = r >> 2, pr = r & 3;
        int t, b2;
        if (blk < 24) { t = 0; b2 = blk; }
        else          { t = 1 + (blk - 24) / 12; b2 = (blk - 24) % 12; }
        int h, nt, ks;
        if (t == 0) { h = b2 / 6; int rem = b2 % 6; nt = rem >> 1; ks = rem & 1; }
        else        { h = b2 / 3; nt = b2 % 3; ks = 0; }
        const float* P = (t==0)?Pph:(t==1)?Pob:(t==2)?Pmi:(t==3)?Ppr:Pse;
        int d = (t==0)?64:(t==1)?32:16;
        int c = nt * 64 + h * 16 + (lane & 15);
        float v[2] = {0.f, 0.f};
#pragma unroll
        for (int e = 0; e < 2; e++) {
            int k = ks * 32 + ((lane >> 4) << 3) + pr * 2 + e;
            if (k < d) {
                float s = 0.f;
                for (int u = 0; u < 64; u++) s += Wqkv[c*64 + u] * P[u*d + k];
                v[e] = s;
            }
        }
        ws[idx] = pk_rne(v[0], v[1]);
    } else if (idx < W_WPW) {
        // merged-K=64 Wo fragments: blocks [ks2(2)][nt(4)] = 8; rest zero.
        int w2 = idx - W_WOW, blk = w2 >> 8, r = w2 & 255, lane = r >> 2, pr = r & 3;
        if (blk < 8) {
            int ks2 = blk >> 2, nt = blk & 3;
            int n = nt * 16 + (lane & 15);
            float v[2];
#pragma unroll
            for (int e = 0; e < 2; e++) {
                int k = ks2 * 32 + ((lane >> 4) << 3) + pr * 2 + e;
                int h = k >> 4, d = k & 15;
                v[e] = Wo[n*64 + h*16 + d];
            }
            ws[idx] = pk_rne(v[0], v[1]);
        } else ws[idx] = 0;
    } else if (idx < W_ENCB) {
        int w2 = idx - W_WPW, blk = w2 >> 8, r = w2 & 255, lane = r >> 2, pr = r & 3;
        int nt = blk >> 1, ks = blk & 1;
        int n = nt * 16 + (lane & 15);
        float v[2];
#pragma unroll
        for (int e = 0; e < 2; e++) {
            int k = ks * 32 + ((lane >> 4) << 3) + pr * 2 + e;
            v[e] = Wp[n*64 + k];
        }
        ws[idx] = pk_rne(v[0], v[1]);
    } else if (idx < W_TOKB) {
        int n = idx - W_ENCB;
        wsf[idx] = (n<64)?bph[n]:(n<96)?bob[n-64]:(n<112)?bmi[n-96]:(n<128)?bpr[n-112]:bse[n-128];
    } else if (idx < W_QKVB) {
        int r = idx - W_TOKB, t = r >> 6, u = r & 63;
        const float* pb = (t==0)?pbph:(t==1)?pbob:(t==2)?pbmi:(t==3)?pbpr:pbse;
        wsf[idx] = pb[u] + bo[u];
    } else if (idx < W_BPB) {
        int r = idx - W_QKVB, t = r / 192, c = r % 192;
        const float* pb = (t==0)?pbph:(t==1)?pbob:(t==2)?pbmi:(t==3)?pbpr:pbse;
        float s = bqkv[c];
        for (int u = 0; u < 64; u++) s += Wqkv[c*64 + u] * pb[u];
        wsf[idx] = s;
    } else {
        wsf[idx] = bp[idx - W_BPB];
    }
}

// ---------------------------------------------------------------------------
// shared helpers
// ---------------------------------------------------------------------------
__device__ __forceinline__ f32x4 MFMA(f16x8 a, f16x8 b, f32x4 c) {
    return __builtin_amdgcn_mfma_f32_16x16x32_f16(
        __builtin_bit_cast(mfma8, a), __builtin_bit_cast(mfma8, b), c, 0, 0, 0);
}

__device__ __forceinline__ f16x8 ldB(const unsigned* __restrict__ W, int wordBase, int blk, int lane) {
    uint4 v = *((const uint4*)(W + wordBase) + (blk * 64 + lane));
    return __builtin_bit_cast(f16x8, v);
}

__device__ __forceinline__ f16x8 ldA(const f16* p, int stride, int row, int kbase, int lg) {
    return *(const f16x8*)(p + row * stride + kbase + lg * 8);
}

__device__ __forceinline__ void stC16(f16* base, int stride, int m0, int col0,
                                      f32x4 c, int l15, int lg) {
    int col = col0 + l15;
    int r0  = m0 + lg * 4;
#pragma unroll
    for (int r = 0; r < 4; r++) base[(r0 + r) * stride + col] = (f16)c[r];
}

// ---------------------------------------------------------------------------
// Kernel A: enc + per-head QKV + attention -> ctx to global ws.
// (round-7 structure; scores via packed fdot2)
// ---------------------------------------------------------------------------
extern "C" __global__ void __launch_bounds__(256, 2) k_mainA(
    const float* __restrict__ x, const unsigned* __restrict__ W,
    unsigned* __restrict__ ctxg)
{
    __shared__ __align__(16) f16 f_lds[64 * 168];    // 21504 B
    __shared__ __align__(16) char dyn[30976];        // xb | qkv stripes [64][242]

    const int tid  = threadIdx.x;
    const int lane = tid & 63;
    const int wv   = tid >> 6;
    const int l15  = lane & 15;
    const int lg   = lane >> 4;

    const float* wsf   = (const float*)W;
    const float* encb  = wsf + W_ENCB;
    const float* qkvbp = wsf + W_QKVB;

    // ---- phase 0: zero f + xb, stage x -> xb (fp16, stride 72) ------------
    {
        unsigned* fu = (unsigned*)f_lds;
        for (int i = tid; i < 5376; i += 256) fu[i] = 0;
        unsigned* du = (unsigned*)dyn;
        for (int i = tid; i < 2304; i += 256) du[i] = 0;
    }
    __syncthreads();
    {
        f16* xb = (f16*)dyn;
        const float* xp = x + (size_t)blockIdx.x * (64 * 58);
        for (int i = tid; i < 3712; i += 256) {
            int s = i / 58, k = i - s * 58;
            xb[s * 72 + k] = (f16)xp[i];
        }
    }
    __syncthreads();

    // ---- phase 1: encoders via MFMA, relu -> f_lds ------------------------
    {
        f32x4 accE[3][4];
#pragma unroll
        for (int i = 0; i < 3; i++) {
            int nt = wv + i * 4;
            if (nt < 9) {
                float be = encb[nt * 16 + l15];
#pragma unroll
                for (int mt = 0; mt < 4; mt++) accE[i][mt] = (f32x4){be, be, be, be};
            }
        }
#pragma unroll
        for (int ks = 0; ks < 2; ks++) {
            f16x8 a[4];
#pragma unroll
            for (int mt = 0; mt < 4; mt++) {
                const char* p = dyn + (mt * 16 + l15) * 144 + ks * 64 + lg * 16;
                a[mt] = *(const f16x8*)p;
            }
#pragma unroll
            for (int i = 0; i < 3; i++) {
                int nt = wv + i * 4;
                if (nt < 9) {
                    f16x8 b = ldB(W, W_EW, nt * 2 + ks, lane);
#pragma unroll
                    for (int mt = 0; mt < 4; mt++) accE[i][mt] = MFMA(a[mt], b, accE[i][mt]);
                }
            }
        }
#pragma unroll
        for (int i = 0; i < 3; i++) {
            int nt = wv + i * 4;
            if (nt < 9) {
#pragma unroll
                for (int mt = 0; mt < 4; mt++) {
                    f32x4 c = accE[i][mt];
#pragma unroll
                    for (int r = 0; r < 4; r++) c[r] = fmaxf(c[r], 0.f);
                    stC16(f_lds, 168, mt * 16, nt * 16, c, l15, lg);
                }
            }
        }
    }
    __syncthreads();

    f16* qkv = (f16*)dyn;
    const int tokOff[5] = {0, 64, 96, 112, 128};

    // ---- do_qkv (round-1 verbatim; stripe cols: q t*48 | k t*48+16 | v +32)
    auto do_qkv = [&](int h) {
        const int qkvBase[5] = {0, 24, 36, 48, 60};
#pragma unroll
        for (int t = 0; t < 5; t++) {
            f32x4 aq[3];
#pragma unroll
            for (int nt = 0; nt < 3; nt++) {
                float bb = qkvbp[t * 192 + nt * 64 + h * 16 + l15];
                aq[nt] = (f32x4){bb, bb, bb, bb};
            }
#pragma unroll
            for (int ks = 0; ks < 2; ks++) {
                if (ks == 0 || t == 0) {
                    f16x8 a = ldA(f_lds, 168, wv * 16 + l15, tokOff[t] + ks * 32, lg);
#pragma unroll
                    for (int nt = 0; nt < 3; nt++) {
                        int blk = qkvBase[t] + ((t == 0) ? (h * 6 + nt * 2 + ks) : (h * 3 + nt));
                        f16x8 b = ldB(W, W_QKVW, blk, lane);
                        aq[nt] = MFMA(a, b, aq[nt]);
                    }
                }
            }
#pragma unroll
            for (int nt = 0; nt < 3; nt++)
                stC16(qkv, 242, wv * 16, t * 48 + nt * 16, aq[nt], l15, lg);
        }
    };

    // ---- do_att (round-7 structure; scores via packed fdot2) ---------------
    auto do_att = [&](int h) {
        const int s    = tid & 63;
        const int role = wv;
        const int sglob = blockIdx.x * 64 + s;
        const f16x2* qr2 = (const f16x2*)(qkv + s * 242);
        f16x2 q0[8];
        f16x2 q4[8];
#pragma unroll
        for (int d2 = 0; d2 < 8; d2++) q0[d2] = qr2[role * 24 + d2];
        if (role == 0) {
#pragma unroll
            for (int d2 = 0; d2 < 8; d2++) q4[d2] = qr2[96 + d2];
        }
        float p0[5], p4[5];
#pragma unroll
        for (int j = 0; j < 5; j++) {
            float a0 = 0.f, a4 = 0.f;
#pragma unroll
            for (int d2 = 0; d2 < 8; d2++) {
                f16x2 kp = qr2[j * 24 + 8 + d2];
                a0 = fdot2(q0[d2], kp, a0);
                if (role == 0) a4 = fdot2(q4[d2], kp, a4);
            }
            p0[j] = a0 * 0.25f; p4[j] = a4 * 0.25f;
        }
        auto softmax5 = [](float* sc) {
            float m = fmaxf(fmaxf(fmaxf(sc[0], sc[1]), fmaxf(sc[2], sc[3])), sc[4]);
            float l = 0.f;
#pragma unroll
            for (int j = 0; j < 5; j++) { sc[j] = __expf(sc[j] - m); l += sc[j]; }
            float r = 1.f / l;
#pragma unroll
            for (int j = 0; j < 5; j++) sc[j] *= r;
        };
        softmax5(p0);
        if (role == 0) softmax5(p4);
        float c0[16], c4[16];
#pragma unroll
        for (int d = 0; d < 16; d++) { c0[d] = 0.f; c4[d] = 0.f; }
#pragma unroll
        for (int j = 0; j < 5; j++) {
#pragma unroll
            for (int d2 = 0; d2 < 8; d2++) {
                f16x2 vp = qr2[j * 24 + 16 + d2];
                float v0 = (float)vp.x, v1 = (float)vp.y;
                c0[2*d2]   += p0[j] * v0;
                c0[2*d2+1] += p0[j] * v1;
                if (role == 0) { c4[2*d2] += p4[j] * v0; c4[2*d2+1] += p4[j] * v1; }
            }
        }
        auto wrctx = [&](int i, const float* c) {
            unsigned* cg = ctxg + OFF_CTX + (size_t)(h * 40 + i * 8) * B_TOTAL + sglob;
#pragma unroll
            for (int d2 = 0; d2 < 8; d2++)
                cg[(size_t)d2 * B_TOTAL] = pk_rne(c[2*d2], c[2*d2+1]);
        };
        wrctx(role, c0);
        if (role == 0) wrctx(4, c4);
    };

    // ---- phase 2: head pipeline (2 barriers/head, no wo) ------------------
    do_qkv(0);
    __syncthreads();
    for (int h = 0; h < 4; h++) {
        do_att(h);
        __syncthreads();            // stripe reads done before next head's writes
        if (h < 3) { do_qkv(h + 1); __syncthreads(); }
    }
}

// ---------------------------------------------------------------------------
// Kernel B: ctx prefetched AFTER phase-0 (enc compute hides the latency);
//           enc recompute + tok-proj + merged Wo (K=64) + LN + pool + Wp.
// (byte-identical to round 9)
// ---------------------------------------------------------------------------
extern "C" __global__ void __launch_bounds__(256, 2) k_mainB(
    const float* __restrict__ x,
    const float* __restrict__ gamma, const float* __restrict__ beta,
    const unsigned* __restrict__ W, float* __restrict__ out)
{
    __shared__ __align__(16) f16 f_lds[64 * 168];    // 21504 B
    __shared__ __align__(16) char dyn[9216];         // xb | plA  [64][72] f16

    const int tid  = threadIdx.x;
    const int lane = tid & 63;
    const int wv   = tid >> 6;
    const int l15  = lane & 15;
    const int lg   = lane >> 4;

    const float* wsf   = (const float*)W;
    const float* encb  = wsf + W_ENCB;
    const float* tokbp = wsf + W_TOKB;
    const float* bpp   = wsf + W_BPB;

    // ---- phase 0: zero f + xb, stage x ------------------------------------
    {
        unsigned* fu = (unsigned*)f_lds;
        for (int i = tid; i < 5376; i += 256) fu[i] = 0;
        unsigned* du = (unsigned*)dyn;
        for (int i = tid; i < 2304; i += 256) du[i] = 0;
    }
    __syncthreads();
    {
        f16* xb = (f16*)dyn;
        const float* xp = x + (size_t)blockIdx.x * (64 * 58);
        for (int i = tid; i < 3712; i += 256) {
            int s = i / 58, k = i - s * 58;
            xb[s * 72 + k] = (f16)xp[i];
        }
    }
    __syncthreads();

    // ---- ISSUE ctx loads here: no barrier until after the encoder MFMAs,
    // so the forced vmcnt drain at the post-enc barrier has ~18 MFMAs +
    // LDS traffic of cover. 10 uint4 = 40 VGPRs live through phase 1.
    uint4 ctxr[2][5];
    {
        const int sg = blockIdx.x * 64 + wv * 16 + l15;
#pragma unroll
        for (int ks2 = 0; ks2 < 2; ks2++) {
            const int hh = ks2 * 2 + (lg >> 1);
#pragma unroll
            for (int t = 0; t < 5; t++) {
                const unsigned* cp = W + OFF_CTX +
                    (size_t)(hh * 40 + t * 8 + (lg & 1) * 4) * B_TOTAL + sg;
                ctxr[ks2][t].x = cp[0];
                ctxr[ks2][t].y = cp[(size_t)B_TOTAL];
                ctxr[ks2][t].z = cp[(size_t)2 * B_TOTAL];
                ctxr[ks2][t].w = cp[(size_t)3 * B_TOTAL];
            }
        }
    }

    // ---- phase 1: encoders (identical to A -> bit-identical f) ------------
    {
        f32x4 accE[3][4];
#pragma unroll
        for (int i = 0; i < 3; i++) {
            int nt = wv + i * 4;
            if (nt < 9) {
                float be = encb[nt * 16 + l15];
#pragma unroll
                for (int mt = 0; mt < 4; mt++) accE[i][mt] = (f32x4){be, be, be, be};
            }
        }
#pragma unroll
        for (int ks = 0; ks < 2; ks++) {
            f16x8 a[4];
#pragma unroll
            for (int mt = 0; mt < 4; mt++) {
                const char* p = dyn + (mt * 16 + l15) * 144 + ks * 64 + lg * 16;
                a[mt] = *(const f16x8*)p;
            }
#pragma unroll
            for (int i = 0; i < 3; i++) {
                int nt = wv + i * 4;
                if (nt < 9) {
                    f16x8 b = ldB(W, W_EW, nt * 2 + ks, lane);
#pragma unroll
                    for (int mt = 0; mt < 4; mt++) accE[i][mt] = MFMA(a[mt], b, accE[i][mt]);
                }
            }
        }
#pragma unroll
        for (int i = 0; i < 3; i++) {
            int nt = wv + i * 4;
            if (nt < 9) {
#pragma unroll
                for (int mt = 0; mt < 4; mt++) {
                    f32x4 c = accE[i][mt];
#pragma unroll
                    for (int r = 0; r < 4; r++) c[r] = fmaxf(c[r], 0.f);
                    stC16(f_lds, 168, mt * 16, nt * 16, c, l15, lg);
                }
            }
        }
    }
    __syncthreads();

    // ---- phase 2: h-frags = tok-proj + merged Wo --------------------------
    f32x4 hf[5][4];
    const int tokOff[5] = {0, 64, 96, 112, 128};

    {   // token projection (round-1 verbatim)
        const int tokBase[5] = {0, 8, 12, 16, 20};
#pragma unroll
        for (int t = 0; t < 5; t++)
#pragma unroll
            for (int nt = 0; nt < 4; nt++) {
                float bb = tokbp[t * 64 + nt * 16 + l15];
                hf[t][nt] = (f32x4){bb, bb, bb, bb};
            }
#pragma unroll
        for (int t = 0; t < 5; t++) {
#pragma unroll
            for (int ks = 0; ks < 2; ks++) {
                if (ks == 0 || t == 0) {
                    f16x8 a = ldA(f_lds, 168, wv * 16 + l15, tokOff[t] + ks * 32, lg);
#pragma unroll
                    for (int nt = 0; nt < 4; nt++) {
                        int blk = (t == 0) ? (nt * 2 + ks) : (tokBase[t] + nt);
                        f16x8 b = ldB(W, W_TOKW, blk, lane);
                        hf[t][nt] = MFMA(a, b, hf[t][nt]);
                    }
                }
            }
        }
    }

    {   // merged Wo: hf[t][nt] += ctx(t) @ Wo, K=64 over (head,dim)
#pragma unroll
        for (int ks2 = 0; ks2 < 2; ks2++) {
            f16x8 bfr[4];
#pragma unroll
            for (int nt = 0; nt < 4; nt++) bfr[nt] = ldB(W, W_WOW, ks2 * 4 + nt, lane);
#pragma unroll
            for (int t = 0; t < 5; t++) {
                f16x8 a = __builtin_bit_cast(f16x8, ctxr[ks2][t]);
#pragma unroll
                for (int nt = 0; nt < 4; nt++) hf[t][nt] = MFMA(a, bfr[nt], hf[t][nt]);
            }
        }
    }

    // ---- phase 3: LN per (sample, token), pool ----------------------------
    float g4[4], b4[4];
#pragma unroll
    for (int nt = 0; nt < 4; nt++) { g4[nt] = gamma[nt * 16 + l15]; b4[nt] = beta[nt * 16 + l15]; }
    f32x4 pool[4];
#pragma unroll
    for (int nt = 0; nt < 4; nt++) pool[nt] = (f32x4){0.f, 0.f, 0.f, 0.f};
#pragma unroll
    for (int t = 0; t < 5; t++) {
#pragma unroll
        for (int r = 0; r < 4; r++) {
            float sm = hf[t][0][r] + hf[t][1][r] + hf[t][2][r] + hf[t][3][r];
            sm += __shfl_xor(sm, 1); sm += __shfl_xor(sm, 2);
            sm += __shfl_xor(sm, 4); sm += __shfl_xor(sm, 8);
            float mu = sm * 0.015625f;
            float vs = 0.f;
#pragma unroll
            for (int nt = 0; nt < 4; nt++) { float d = hf[t][nt][r] - mu; vs += d * d; }
            vs += __shfl_xor(vs, 1); vs += __shfl_xor(vs, 2);
            vs += __shfl_xor(vs, 4); vs += __shfl_xor(vs, 8);
            float rs = rsqrtf(vs * 0.015625f + 1e-5f);
#pragma unroll
            for (int nt = 0; nt < 4; nt++)
                pool[nt][r] += (hf[t][nt][r] - mu) * rs * g4[nt] + b4[nt];
        }
    }
    __syncthreads();   // all xb/enc traffic long done; reuse dyn for plA
    {
        f16* plA = (f16*)dyn;
#pragma unroll
        for (int nt = 0; nt < 4; nt++) {
#pragma unroll
            for (int r = 0; r < 4; r++)
                plA[(wv * 16 + lg * 4 + r) * 72 + nt * 16 + l15] = (f16)(pool[nt][r] * 0.2f);
        }
    }
    __syncthreads();

    // ---- phase 4: out = relu(pooled @ Wp^T + bp), direct stores -----------
    {
        f32x4 accP[8];
#pragma unroll
        for (int n2 = 0; n2 < 8; n2++) {
            float bb = bpp[n2 * 16 + l15];
            accP[n2] = (f32x4){bb, bb, bb, bb};
        }
#pragma unroll
        for (int ks = 0; ks < 2; ks++) {
            const char* p = dyn + (wv * 16 + l15) * 144 + ks * 64 + lg * 16;
            f16x8 a = *(const f16x8*)p;
#pragma unroll
            for (int n2 = 0; n2 < 8; n2++) {
                f16x8 b = ldB(W, W_WPW, n2 * 2 + ks, lane);
                accP[n2] = MFMA(a, b, accP[n2]);
            }
        }
        float* og = out + (size_t)blockIdx.x * (64 * 128);
#pragma unroll
        for (int n2 = 0; n2 < 8; n2++) {
#pragma unroll
            for (int r = 0; r < 4; r++)
                og[(wv * 16 + lg * 4 + r) * 128 + n2 * 16 + l15] = fmaxf(accP[n2][r], 0.f);
        }
    }
}

// ---------------------------------------------------------------------------
extern "C" void kernel_launch(void* const* d_in, const int* in_sizes, int n_in,
                              void* d_out, int out_size, void* d_ws, size_t ws_size,
                              hipStream_t stream)
{
    const float* x      = (const float*)d_in[0];
    const float* W_phys = (const float*)d_in[1];
    const float* b_phys = (const float*)d_in[2];
    const float* W_obj  = (const float*)d_in[3];
    const float* b_obj  = (const float*)d_in[4];
    const float* W_mine = (const float*)d_in[5];
    const float* b_mine = (const float*)d_in[6];
    const float* W_prog = (const float*)d_in[7];
    const float* b_prog = (const float*)d_in[8];
    const float* W_seq  = (const float*)d_in[9];
    const float* b_seq  = (const float*)d_in[10];
    const float* P_phys = (const float*)d_in[11];
    const float* pb_phys= (const float*)d_in[12];
    const float* P_obj  = (const float*)d_in[13];
    const float* pb_obj = (const float*)d_in[14];
    const float* P_mine = (const float*)d_in[15];
    const float* pb_mine= (const float*)d_in[16];
    const float* P_prog = (const float*)d_in[17];
    const float* pb_prog= (const float*)d_in[18];
    const float* P_seq  = (const float*)d_in[19];
    const float* pb_seq = (const float*)d_in[20];
    const float* Wqkv   = (const float*)d_in[21];
    const float* bqkv   = (const float*)d_in[22];
    const float* Wo     = (const float*)d_in[23];
    const float* bo     = (const float*)d_in[24];
    const float* gamma  = (const float*)d_in[25];
    const float* beta   = (const float*)d_in[26];
    const float* Wp     = (const float*)d_in[27];
    const float* bp     = (const float*)d_in[28];

    unsigned* ws = (unsigned*)d_ws;

    k_prep<<<(W_TOTAL + 255) / 256, 256, 0, stream>>>(
        W_phys, b_phys, W_obj, b_obj, W_mine, b_mine, W_prog, b_prog, W_seq, b_seq,
        P_phys, pb_phys, P_obj, pb_obj, P_mine, pb_mine, P_prog, pb_prog, P_seq, pb_seq,
        Wqkv, bqkv, Wo, bo, Wp, bp, ws);

    k_mainA<<<NBLK, 256, 0, stream>>>(x, ws, ws);
    k_mainB<<<NBLK, 256, 0, stream>>>(x, gamma, beta, ws, (float*)d_out);
}